// Round 1
// baseline (492.470 us; speedup 1.0000x reference)
//
#include <hip/hip_runtime.h>

#define HH 512
#define WW 512
#define NB 4

// ---------------- Stage 1: 11x11 convs (1->8, pos & neg) + spike/WTA logic ----------------
#define K1 11
#define PAD1 5
#define T1 32
#define IN1 (T1 + K1 - 1)  // 42

__global__ __launch_bounds__(256) void stage1_kernel(
    const float* __restrict__ inp, const float* __restrict__ Wb,
    unsigned char* __restrict__ border)
{
    __shared__ float s0[IN1 * IN1];
    __shared__ float s1[IN1 * IN1];
    __shared__ float wsh[8 * K1 * K1];

    const int b   = blockIdx.z;
    const int tx0 = blockIdx.x * T1;
    const int ty0 = blockIdx.y * T1;
    const float* in0 = inp + ((size_t)b * 2 + 0) * (HH * WW);
    const float* in1 = inp + ((size_t)b * 2 + 1) * (HH * WW);

    for (int i = threadIdx.x; i < 8 * K1 * K1; i += 256) wsh[i] = Wb[i];
    for (int i = threadIdx.x; i < IN1 * IN1; i += 256) {
        int iy = i / IN1, ix = i - iy * IN1;
        int gy = ty0 + iy - PAD1, gx = tx0 + ix - PAD1;
        bool ok = (gy >= 0) & (gy < HH) & (gx >= 0) & (gx < WW);
        int idx = gy * WW + gx;
        s0[i] = ok ? in0[idx] : 0.f;
        s1[i] = ok ? in1[idx] : 0.f;
    }
    __syncthreads();

    const int lx = threadIdx.x & 7;   // 8 groups of 4 pixels -> 32 wide
    const int ly = threadIdx.x >> 3;  // 32 rows
    const int px = lx * 4;
    const int py = ly;

    float accP[8][4];
    float accN[8][4];
    #pragma unroll
    for (int c = 0; c < 8; c++)
        #pragma unroll
        for (int p = 0; p < 4; p++) { accP[c][p] = 0.f; accN[c][p] = 0.f; }

    for (int ky = 0; ky < K1; ky++) {
        const float* r0 = &s0[(py + ky) * IN1 + px];
        const float* r1 = &s1[(py + ky) * IN1 + px];
        float a0 = r0[0], a1 = r0[1], a2 = r0[2], a3 = r0[3];
        float c0 = r1[0], c1 = r1[1], c2 = r1[2], c3 = r1[3];
        #pragma unroll
        for (int kx = 0; kx < K1; kx++) {
            #pragma unroll
            for (int c = 0; c < 8; c++) {
                float wv = wsh[c * (K1 * K1) + ky * K1 + kx];
                accP[c][0] = fmaf(a0, wv, accP[c][0]);
                accP[c][1] = fmaf(a1, wv, accP[c][1]);
                accP[c][2] = fmaf(a2, wv, accP[c][2]);
                accP[c][3] = fmaf(a3, wv, accP[c][3]);
                accN[c][0] = fmaf(c0, wv, accN[c][0]);
                accN[c][1] = fmaf(c1, wv, accN[c][1]);
                accN[c][2] = fmaf(c2, wv, accN[c][2]);
                accN[c][3] = fmaf(c3, wv, accN[c][3]);
            }
            if (kx < K1 - 1) {
                a0 = a1; a1 = a2; a2 = a3; a3 = r0[kx + 4];
                c0 = c1; c1 = c2; c2 = c3; c3 = r1[kx + 4];
            }
        }
    }

    const int gy = ty0 + py;
    const int gxbase = tx0 + px;

    float chv[16][4];
    #pragma unroll
    for (int p = 0; p < 4; p++) {
        float vm = s0[(py + PAD1) * IN1 + px + PAD1 + p]
                 + s1[(py + PAD1) * IN1 + px + PAD1 + p];
        float pe[4], po[4], ne[4], no[4];
        #pragma unroll
        for (int o = 0; o < 4; o++) {
            pe[o] = (accP[2 * o][p]     >= 1.f) ? 1.f : 0.f;
            po[o] = (accP[2 * o + 1][p] >= 1.f) ? 1.f : 0.f;
            ne[o] = (accN[2 * o][p]     >= 1.f) ? 1.f : 0.f;
            no[o] = (accN[2 * o + 1][p] >= 1.f) ? 1.f : 0.f;
        }
        float b13[4], b24[4], tp[4];
        float mx = 0.f;
        #pragma unroll
        for (int o = 0; o < 4; o++) {
            float sa = (vm * (pe[o] - 1.5f * no[o]) >= 1.f) ? 1.f : 0.f;
            float sb = (vm * (ne[o] - 1.5f * po[o]) >= 1.f) ? 1.f : 0.f;
            b13[o] = sa + sb;
            float sc = (vm * (po[o] - 1.5f * ne[o]) >= 1.f) ? 1.f : 0.f;
            float sd = (vm * (no[o] - 1.5f * pe[o]) >= 1.f) ? 1.f : 0.f;
            b24[o] = sc + sd;
            tp[o] = fabsf(b13[o] - b24[o]);
            mx = fmaxf(mx, tp[o]);
        }
        #pragma unroll
        for (int o = 0; o < 4; o++) {
            float d   = b13[o] - b24[o];
            float wta = (tp[o] == mx) ? 1.f : 0.f;
            float b1p = (wta * d >= 1.f)    ? 1.f : 0.f;
            float b1n = (-(wta * d) >= 1.f) ? 1.f : 0.f;
            chv[4 * o + 0][p] = b1p * b13[o];
            chv[4 * o + 1][p] = b1p * b24[o];  // G_INH = 1.0
            chv[4 * o + 2][p] = b1n * b24[o];
            chv[4 * o + 3][p] = b1n * b13[o];  // G_INH = 1.0
        }
    }
    #pragma unroll
    for (int k = 0; k < 16; k++) {
        unsigned int w32 = (unsigned int)(unsigned char)chv[k][0]
                         | ((unsigned int)(unsigned char)chv[k][1] << 8)
                         | ((unsigned int)(unsigned char)chv[k][2] << 16)
                         | ((unsigned int)(unsigned char)chv[k][3] << 24);
        *(unsigned int*)&border[(((size_t)b * 16 + k) * HH + gy) * WW + gxbase] = w32;
    }
}

// ---------------- Stage 2: depthwise 23x23 conv (16 ch) + spike + combine ----------------
#define K2 23
#define PAD2 11
#define T2X 64
#define T2Y 32
#define IN2X (T2X + K2 - 1)  // 86
#define IN2Y (T2Y + K2 - 1)  // 54

__global__ __launch_bounds__(256) void stage2_kernel(
    const unsigned char* __restrict__ border, const float* __restrict__ Wg,
    float* __restrict__ out)
{
    __shared__ float tile[IN2Y * IN2X];  // 4644 f32 = 18.6 KB
    __shared__ float wsh[K2 * K2];

    const int b   = blockIdx.z;
    const int tx0 = blockIdx.x * T2X;
    const int ty0 = blockIdx.y * T2Y;
    const int lx = threadIdx.x & 7;   // 8 groups of 8 pixels -> 64 wide
    const int ly = threadIdx.x >> 3;  // 32 rows
    const int px = lx * 8;
    const int py = ly;

    float acc_out[8];
    float prev[8];
    #pragma unroll
    for (int p = 0; p < 8; p++) { acc_out[p] = 0.f; prev[p] = 0.f; }

    #pragma unroll 1
    for (int c = 0; c < 16; c++) {
        const unsigned char* bp = border + ((size_t)b * 16 + c) * (HH * WW);
        for (int i = threadIdx.x; i < K2 * K2; i += 256) wsh[i] = Wg[c * (K2 * K2) + i];
        for (int i = threadIdx.x; i < IN2Y * IN2X; i += 256) {
            int iy = i / IN2X, ix = i - iy * IN2X;
            int gy = ty0 + iy - PAD2, gx = tx0 + ix - PAD2;
            bool ok = (gy >= 0) & (gy < HH) & (gx >= 0) & (gx < WW);
            tile[i] = ok ? (float)bp[gy * WW + gx] : 0.f;
        }
        __syncthreads();

        float acc[8];
        #pragma unroll
        for (int p = 0; p < 8; p++) acc[p] = 0.f;

        for (int ky = 0; ky < K2; ky++) {
            const float* row = &tile[(py + ky) * IN2X + px];
            float w0 = row[0], w1 = row[1], w2 = row[2], w3 = row[3];
            float w4 = row[4], w5 = row[5], w6 = row[6], w7 = row[7];
            #pragma unroll
            for (int kx = 0; kx < K2; kx++) {
                float wv = wsh[ky * K2 + kx];
                acc[0] = fmaf(w0, wv, acc[0]);
                acc[1] = fmaf(w1, wv, acc[1]);
                acc[2] = fmaf(w2, wv, acc[2]);
                acc[3] = fmaf(w3, wv, acc[3]);
                acc[4] = fmaf(w4, wv, acc[4]);
                acc[5] = fmaf(w5, wv, acc[5]);
                acc[6] = fmaf(w6, wv, acc[6]);
                acc[7] = fmaf(w7, wv, acc[7]);
                if (kx < K2 - 1) {
                    w0 = w1; w1 = w2; w2 = w3; w3 = w4;
                    w4 = w5; w5 = w6; w6 = w7; w7 = row[kx + 8];
                }
            }
        }
        #pragma unroll
        for (int p = 0; p < 8; p++) {
            float gs = (acc[p] >= 1.f) ? 1.f : 0.f;
            if ((c & 1) == 0) prev[p] = gs;
            else              acc_out[p] += prev[p] * (1.f - gs);  // spike(gs_prev - gs)
        }
        __syncthreads();
    }

    const int gy = ty0 + py;
    const int gx0 = tx0 + px;
    float* op = out + ((size_t)b) * (HH * WW) + (size_t)gy * WW + gx0;
    #pragma unroll
    for (int p = 0; p < 8; p++) op[p] = acc_out[p];
}

extern "C" void kernel_launch(void* const* d_in, const int* in_sizes, int n_in,
                              void* d_out, int out_size, void* d_ws, size_t ws_size,
                              hipStream_t stream)
{
    const float* inp = (const float*)d_in[0];   // (4,2,512,512) f32
    const float* Wb  = (const float*)d_in[1];   // (8,1,11,11)   f32
    const float* Wg  = (const float*)d_in[2];   // (16,1,23,23)  f32
    unsigned char* border = (unsigned char*)d_ws;  // (4,16,512,512) u8 = 16.8 MB
    float* out = (float*)d_out;                 // (4,512,512)   f32

    dim3 blk(256);
    dim3 g1(WW / T1, HH / T1, NB);    // 16x16x4
    stage1_kernel<<<g1, blk, 0, stream>>>(inp, Wb, border);
    dim3 g2(WW / T2X, HH / T2Y, NB);  // 8x16x4
    stage2_kernel<<<g2, blk, 0, stream>>>(border, Wg, out);
}

// Round 2
// 438.050 us; speedup vs baseline: 1.1242x; 1.1242x over previous
//
#include <hip/hip_runtime.h>

#define HH 512
#define WW 512
#define NB 4

// ---------------- Stage 1: 11x11 convs (1->8, pos & neg) + spike/WTA logic ----------------
#define K1 11
#define PAD1 5
#define T1 32
#define IN1 42        // 32 + 10 halo
#define S1 44         // LDS row stride (floats): mult of 4 (16B align), 44%32=12 -> even bank tiling

__global__ __launch_bounds__(256) void stage1_kernel(
    const float* __restrict__ inp, const float* __restrict__ Wb,
    unsigned char* __restrict__ border)
{
    __shared__ __align__(16) float s0[IN1 * S1];
    __shared__ __align__(16) float s1[IN1 * S1];
    __shared__ __align__(16) float wp[K1 * 8 * 12];   // [ky][c][12] padded rows

    const int b   = blockIdx.z;
    const int tx0 = blockIdx.x * T1;
    const int ty0 = blockIdx.y * T1;
    const float* in0 = inp + ((size_t)b * 2 + 0) * (HH * WW);
    const float* in1 = inp + ((size_t)b * 2 + 1) * (HH * WW);

    // weight repack: Wb[c][ky][kx] -> wp[(ky*8+c)*12 + kx]
    for (int i = threadIdx.x; i < 8 * K1 * K1; i += 256) {
        int c = i / 121, r = i - c * 121;
        int ky = r / 11, kx = r - ky * 11;
        wp[(ky * 8 + c) * 12 + kx] = Wb[i];
    }
    for (int i = threadIdx.x; i < IN1 * IN1; i += 256) {
        int iy = i / IN1, ix = i - iy * IN1;
        int gy = ty0 + iy - PAD1, gx = tx0 + ix - PAD1;
        bool ok = (gy >= 0) & (gy < HH) & (gx >= 0) & (gx < WW);
        int idx = gy * WW + gx;
        s0[iy * S1 + ix] = ok ? in0[idx] : 0.f;
        s1[iy * S1 + ix] = ok ? in1[idx] : 0.f;
    }
    __syncthreads();

    const int lx = threadIdx.x & 7;   // 8 groups of 4 px -> 32 wide
    const int ly = threadIdx.x >> 3;  // 32 rows
    const int px = lx * 4;
    const int py = ly;

    float accP[8][4];
    float accN[8][4];
    #pragma unroll
    for (int c = 0; c < 8; c++)
        #pragma unroll
        for (int p = 0; p < 4; p++) { accP[c][p] = 0.f; accN[c][p] = 0.f; }

    #pragma unroll 1
    for (int ky = 0; ky < K1; ky++) {
        const float4* r0 = (const float4*)&s0[(py + ky) * S1 + px];
        const float4* r1 = (const float4*)&s1[(py + ky) * S1 + px];
        float a[16], cc[16];
        #pragma unroll
        for (int r = 0; r < 4; r++) {
            *(float4*)&a[4 * r]  = r0[r];
            *(float4*)&cc[4 * r] = r1[r];
        }
        #pragma unroll
        for (int c = 0; c < 8; c++) {
            const float4* wr = (const float4*)&wp[(ky * 8 + c) * 12];
            float w[12];
            #pragma unroll
            for (int r = 0; r < 3; r++) *(float4*)&w[4 * r] = wr[r];
            #pragma unroll
            for (int kx = 0; kx < K1; kx++) {
                float wv = w[kx];
                #pragma unroll
                for (int p = 0; p < 4; p++) {
                    accP[c][p] = fmaf(a[kx + p],  wv, accP[c][p]);
                    accN[c][p] = fmaf(cc[kx + p], wv, accN[c][p]);
                }
            }
        }
    }

    const int gy = ty0 + py;
    const int gxbase = tx0 + px;

    float chv[16][4];
    #pragma unroll
    for (int p = 0; p < 4; p++) {
        float vm = s0[(py + PAD1) * S1 + px + PAD1 + p]
                 + s1[(py + PAD1) * S1 + px + PAD1 + p];
        float pe[4], po[4], ne[4], no[4];
        #pragma unroll
        for (int o = 0; o < 4; o++) {
            pe[o] = (accP[2 * o][p]     >= 1.f) ? 1.f : 0.f;
            po[o] = (accP[2 * o + 1][p] >= 1.f) ? 1.f : 0.f;
            ne[o] = (accN[2 * o][p]     >= 1.f) ? 1.f : 0.f;
            no[o] = (accN[2 * o + 1][p] >= 1.f) ? 1.f : 0.f;
        }
        float b13[4], b24[4], tp[4];
        float mx = 0.f;
        #pragma unroll
        for (int o = 0; o < 4; o++) {
            float sa = (vm * (pe[o] - 1.5f * no[o]) >= 1.f) ? 1.f : 0.f;
            float sb = (vm * (ne[o] - 1.5f * po[o]) >= 1.f) ? 1.f : 0.f;
            b13[o] = sa + sb;
            float sc = (vm * (po[o] - 1.5f * ne[o]) >= 1.f) ? 1.f : 0.f;
            float sd = (vm * (no[o] - 1.5f * pe[o]) >= 1.f) ? 1.f : 0.f;
            b24[o] = sc + sd;
            tp[o] = fabsf(b13[o] - b24[o]);
            mx = fmaxf(mx, tp[o]);
        }
        #pragma unroll
        for (int o = 0; o < 4; o++) {
            float d   = b13[o] - b24[o];
            float wta = (tp[o] == mx) ? 1.f : 0.f;
            float b1p = (wta * d >= 1.f)    ? 1.f : 0.f;
            float b1n = (-(wta * d) >= 1.f) ? 1.f : 0.f;
            chv[4 * o + 0][p] = b1p * b13[o];
            chv[4 * o + 1][p] = b1p * b24[o];  // G_INH = 1.0
            chv[4 * o + 2][p] = b1n * b24[o];
            chv[4 * o + 3][p] = b1n * b13[o];  // G_INH = 1.0
        }
    }
    #pragma unroll
    for (int k = 0; k < 16; k++) {
        unsigned int w32 = (unsigned int)(unsigned char)chv[k][0]
                         | ((unsigned int)(unsigned char)chv[k][1] << 8)
                         | ((unsigned int)(unsigned char)chv[k][2] << 16)
                         | ((unsigned int)(unsigned char)chv[k][3] << 24);
        *(unsigned int*)&border[(((size_t)b * 16 + k) * HH + gy) * WW + gxbase] = w32;
    }
}

// ---------------- Stage 2: depthwise 23x23 conv (16 ch) + spike + combine ----------------
#define K2 23
#define PAD2 11
#define T2X 64
#define T2Y 32
#define IN2X 86        // 64 + 22 halo
#define IN2Y 54        // 32 + 22 halo
#define S2 92          // LDS row stride (floats): mult of 4, 92%32=28 -> even bank tiling

__global__ __launch_bounds__(256) void stage2_kernel(
    const unsigned char* __restrict__ border, const float* __restrict__ Wg,
    float* __restrict__ out)
{
    __shared__ __align__(16) float tile[IN2Y * S2];   // 54*92*4 = 19.9 KB
    __shared__ __align__(16) float wsh[K2 * 24];      // [ky][24] padded rows

    const int b   = blockIdx.z;
    const int tx0 = blockIdx.x * T2X;
    const int ty0 = blockIdx.y * T2Y;
    const int lx = threadIdx.x & 7;   // 8 groups of 8 px -> 64 wide
    const int ly = threadIdx.x >> 3;  // 32 rows
    const int px = lx * 8;
    const int py = ly;

    float acc_out[8];
    float prev[8];
    #pragma unroll
    for (int p = 0; p < 8; p++) { acc_out[p] = 0.f; prev[p] = 0.f; }

    #pragma unroll 1
    for (int c = 0; c < 16; c++) {
        const unsigned char* bp = border + ((size_t)b * 16 + c) * (HH * WW);
        // weight repack: Wg[c][ky][kx] -> wsh[ky*24+kx]
        for (int i = threadIdx.x; i < K2 * K2; i += 256) {
            int ky = i / 23, kx = i - ky * 23;
            wsh[ky * 24 + kx] = Wg[c * (K2 * K2) + i];
        }
        for (int i = threadIdx.x; i < IN2Y * IN2X; i += 256) {
            int iy = i / IN2X, ix = i - iy * IN2X;
            int gy = ty0 + iy - PAD2, gx = tx0 + ix - PAD2;
            bool ok = (gy >= 0) & (gy < HH) & (gx >= 0) & (gx < WW);
            tile[iy * S2 + ix] = ok ? (float)bp[gy * WW + gx] : 0.f;
        }
        __syncthreads();

        float acc[8];
        #pragma unroll
        for (int p = 0; p < 8; p++) acc[p] = 0.f;

        #pragma unroll 1
        for (int ky = 0; ky < K2; ky++) {
            const float4* tp4 = (const float4*)&tile[(py + ky) * S2 + px];
            float a[32];
            #pragma unroll
            for (int r = 0; r < 8; r++) *(float4*)&a[4 * r] = tp4[r];
            const float4* wp4 = (const float4*)&wsh[ky * 24];
            float w[24];
            #pragma unroll
            for (int r = 0; r < 6; r++) *(float4*)&w[4 * r] = wp4[r];
            #pragma unroll
            for (int kx = 0; kx < K2; kx++) {
                float wv = w[kx];
                #pragma unroll
                for (int p = 0; p < 8; p++)
                    acc[p] = fmaf(a[kx + p], wv, acc[p]);
            }
        }
        #pragma unroll
        for (int p = 0; p < 8; p++) {
            float gs = (acc[p] >= 1.f) ? 1.f : 0.f;
            if ((c & 1) == 0) prev[p] = gs;
            else              acc_out[p] += prev[p] * (1.f - gs);  // spike(gs_prev - gs)
        }
        __syncthreads();
    }

    const int gy = ty0 + py;
    const int gx0 = tx0 + px;
    float* op = out + ((size_t)b) * (HH * WW) + (size_t)gy * WW + gx0;
    *(float4*)&op[0] = *(float4*)&acc_out[0];
    *(float4*)&op[4] = *(float4*)&acc_out[4];
}

extern "C" void kernel_launch(void* const* d_in, const int* in_sizes, int n_in,
                              void* d_out, int out_size, void* d_ws, size_t ws_size,
                              hipStream_t stream)
{
    const float* inp = (const float*)d_in[0];   // (4,2,512,512) f32
    const float* Wb  = (const float*)d_in[1];   // (8,1,11,11)   f32
    const float* Wg  = (const float*)d_in[2];   // (16,1,23,23)  f32
    unsigned char* border = (unsigned char*)d_ws;  // (4,16,512,512) u8 = 16.8 MB
    float* out = (float*)d_out;                 // (4,512,512)   f32

    dim3 blk(256);
    dim3 g1(WW / T1, HH / T1, NB);    // 16x16x4 = 1024 blocks
    stage1_kernel<<<g1, blk, 0, stream>>>(inp, Wb, border);
    dim3 g2(WW / T2X, HH / T2Y, NB);  // 8x16x4 = 512 blocks
    stage2_kernel<<<g2, blk, 0, stream>>>(border, Wg, out);
}

// Round 3
// 323.268 us; speedup vs baseline: 1.5234x; 1.3551x over previous
//
#include <hip/hip_runtime.h>

#define HH 512
#define WW 512
#define NB 4

// ---------------- Stage 1: 11x11 convs (1->8, pos & neg) + spike/WTA logic ----------------
#define K1 11
#define PAD1 5
#define T1 32
#define IN1 42        // 32 + 10 halo
#define S1 44         // LDS row stride (floats)

__global__ __launch_bounds__(256) void stage1_kernel(
    const float* __restrict__ inp, const float* __restrict__ Wb,
    unsigned char* __restrict__ border)
{
    __shared__ __align__(16) float s0[IN1 * S1];
    __shared__ __align__(16) float s1[IN1 * S1];

    const int b   = blockIdx.z;
    const int tx0 = blockIdx.x * T1;
    const int ty0 = blockIdx.y * T1;
    const float* in0 = inp + ((size_t)b * 2 + 0) * (HH * WW);
    const float* in1 = inp + ((size_t)b * 2 + 1) * (HH * WW);

    for (int i = threadIdx.x; i < IN1 * IN1; i += 256) {
        int iy = i / IN1, ix = i - iy * IN1;
        int gy = ty0 + iy - PAD1, gx = tx0 + ix - PAD1;
        bool ok = (gy >= 0) & (gy < HH) & (gx >= 0) & (gx < WW);
        int idx = gy * WW + gx;
        s0[iy * S1 + ix] = ok ? in0[idx] : 0.f;
        s1[iy * S1 + ix] = ok ? in1[idx] : 0.f;
    }
    __syncthreads();

    const int lx = threadIdx.x & 7;   // 8 groups of 4 px -> 32 wide
    const int ly = threadIdx.x >> 3;  // 32 rows
    const int px = lx * 4;
    const int py = ly;

    float accP[8][4];
    float accN[8][4];
    #pragma unroll
    for (int c = 0; c < 8; c++)
        #pragma unroll
        for (int p = 0; p < 4; p++) { accP[c][p] = 0.f; accN[c][p] = 0.f; }

    #pragma unroll 1
    for (int ky = 0; ky < K1; ky++) {
        const float4* r0 = (const float4*)&s0[(py + ky) * S1 + px];
        const float4* r1 = (const float4*)&s1[(py + ky) * S1 + px];
        float a[16], cc[16];
        #pragma unroll
        for (int r = 0; r < 4; r++) {
            *(float4*)&a[4 * r]  = r0[r];
            *(float4*)&cc[4 * r] = r1[r];
        }
        #pragma unroll
        for (int c = 0; c < 8; c++) {
            const float* wr = Wb + c * (K1 * K1) + ky * K1;  // uniform -> s_load
            #pragma unroll
            for (int kx = 0; kx < K1; kx++) {
                const float wv = wr[kx];
                #pragma unroll
                for (int p = 0; p < 4; p++) {
                    accP[c][p] = fmaf(a[kx + p],  wv, accP[c][p]);
                    accN[c][p] = fmaf(cc[kx + p], wv, accN[c][p]);
                }
            }
        }
    }

    const int gy = ty0 + py;
    const int gxbase = tx0 + px;

    float chv[16][4];
    #pragma unroll
    for (int p = 0; p < 4; p++) {
        float vm = s0[(py + PAD1) * S1 + px + PAD1 + p]
                 + s1[(py + PAD1) * S1 + px + PAD1 + p];
        float pe[4], po[4], ne[4], no[4];
        #pragma unroll
        for (int o = 0; o < 4; o++) {
            pe[o] = (accP[2 * o][p]     >= 1.f) ? 1.f : 0.f;
            po[o] = (accP[2 * o + 1][p] >= 1.f) ? 1.f : 0.f;
            ne[o] = (accN[2 * o][p]     >= 1.f) ? 1.f : 0.f;
            no[o] = (accN[2 * o + 1][p] >= 1.f) ? 1.f : 0.f;
        }
        float b13[4], b24[4], tp[4];
        float mx = 0.f;
        #pragma unroll
        for (int o = 0; o < 4; o++) {
            float sa = (vm * (pe[o] - 1.5f * no[o]) >= 1.f) ? 1.f : 0.f;
            float sb = (vm * (ne[o] - 1.5f * po[o]) >= 1.f) ? 1.f : 0.f;
            b13[o] = sa + sb;
            float sc = (vm * (po[o] - 1.5f * ne[o]) >= 1.f) ? 1.f : 0.f;
            float sd = (vm * (no[o] - 1.5f * pe[o]) >= 1.f) ? 1.f : 0.f;
            b24[o] = sc + sd;
            tp[o] = fabsf(b13[o] - b24[o]);
            mx = fmaxf(mx, tp[o]);
        }
        #pragma unroll
        for (int o = 0; o < 4; o++) {
            float d   = b13[o] - b24[o];
            float wta = (tp[o] == mx) ? 1.f : 0.f;
            float b1p = (wta * d >= 1.f)    ? 1.f : 0.f;
            float b1n = (-(wta * d) >= 1.f) ? 1.f : 0.f;
            chv[4 * o + 0][p] = b1p * b13[o];
            chv[4 * o + 1][p] = b1p * b24[o];  // G_INH = 1.0
            chv[4 * o + 2][p] = b1n * b24[o];
            chv[4 * o + 3][p] = b1n * b13[o];  // G_INH = 1.0
        }
    }
    #pragma unroll
    for (int k = 0; k < 16; k++) {
        unsigned int w32 = (unsigned int)(unsigned char)chv[k][0]
                         | ((unsigned int)(unsigned char)chv[k][1] << 8)
                         | ((unsigned int)(unsigned char)chv[k][2] << 16)
                         | ((unsigned int)(unsigned char)chv[k][3] << 24);
        *(unsigned int*)&border[(((size_t)b * 16 + k) * HH + gy) * WW + gxbase] = w32;
    }
}

// ---------------- Stage 2: depthwise 23x23 conv, one (batch,channel) plane per block ------
// Tile 64x128 out, thread = 8x * 4y. Loop input rows; each staged row read once per thread
// and feeds 4 output-row accumulators. Weights via uniform (scalar) global loads.
#define K2 23
#define PAD2 11
#define T2X 64
#define T2Y 128
#define S2 88          // LDS cols: global x = tx0-12+col, col 0..87 (16B-aligned reads)
#define R2 150         // staged rows: ty0-11 .. ty0+138

__global__ __launch_bounds__(256) void stage2_kernel(
    const unsigned char* __restrict__ border, const float* __restrict__ Wg,
    unsigned char* __restrict__ gsp)
{
    __shared__ __align__(16) float tile[R2 * S2];   // 52.8 KB -> 3 blocks/CU

    const int z   = blockIdx.z;
    const int b   = z >> 4;
    const int c   = z & 15;
    const int tx0 = blockIdx.x * T2X;
    const int ty0 = blockIdx.y * T2Y;
    const unsigned char* bp = border + ((size_t)b * 16 + c) * (HH * WW);

    // ---- stage u8 -> f32 tile: rows ty0-11.., cols tx0-12.. (4-byte aligned groups) ----
    for (int i = threadIdx.x; i < R2 * (S2 / 4); i += 256) {
        int iy = i / (S2 / 4), c4 = i - iy * (S2 / 4);
        int gy  = ty0 - PAD2 + iy;
        int gx0 = tx0 - 12 + 4 * c4;
        float4 f;
        bool rowok = (unsigned)gy < HH;
        if (rowok & ((unsigned)gx0 < WW)) {      // gx0 % 4 == 0, so gx0<512 => gx0+3<512
            unsigned u = *(const unsigned*)(bp + (size_t)gy * WW + gx0);
            f.x = (float)(u & 255u);
            f.y = (float)((u >> 8) & 255u);
            f.z = (float)((u >> 16) & 255u);
            f.w = (float)(u >> 24);
        } else if (rowok) {
            const unsigned char* rowp = bp + (size_t)gy * WW;
            f.x = ((unsigned)(gx0 + 0) < WW) ? (float)rowp[gx0 + 0] : 0.f;
            f.y = ((unsigned)(gx0 + 1) < WW) ? (float)rowp[gx0 + 1] : 0.f;
            f.z = ((unsigned)(gx0 + 2) < WW) ? (float)rowp[gx0 + 2] : 0.f;
            f.w = ((unsigned)(gx0 + 3) < WW) ? (float)rowp[gx0 + 3] : 0.f;
        } else {
            f.x = f.y = f.z = f.w = 0.f;
        }
        *(float4*)&tile[iy * S2 + 4 * c4] = f;
    }
    __syncthreads();

    const int lx = threadIdx.x & 7;    // 8 x-groups of 8 px -> 64 wide
    const int ly = threadIdx.x >> 3;   // 32 y-groups of 4 rows -> 128 tall
    const int px = lx * 8;
    const int py = ly * 4;

    float acc[4][8];
    #pragma unroll
    for (int dy = 0; dy < 4; dy++)
        #pragma unroll
        for (int p = 0; p < 8; p++) acc[dy][p] = 0.f;

    const float* wc = Wg + c * (K2 * K2);

    #pragma unroll 1
    for (int t = 0; t < 26; t++) {
        // one row window, read once, feeds up to 4 accumulator rows
        const float4* rp = (const float4*)&tile[(py + t) * S2 + px];
        float a[32];
        #pragma unroll
        for (int r = 0; r < 8; r++) *(float4*)&a[4 * r] = rp[r];
        #pragma unroll
        for (int dy = 0; dy < 4; dy++) {
            const int ky = t - dy;
            if (ky >= 0 && ky < K2) {            // wave-uniform branch
                const float* wr = wc + ky * K2;  // uniform -> s_load
                #pragma unroll
                for (int kx = 0; kx < K2; kx++) {
                    const float wv = wr[kx];
                    #pragma unroll
                    for (int p = 0; p < 8; p++)
                        acc[dy][p] = fmaf(a[kx + p + 1], wv, acc[dy][p]);
                }
            }
        }
    }

    // ---- spike + write u8 plane ----
    const int ox = tx0 + px;
    unsigned char* gp = gsp + ((size_t)b * 16 + c) * (HH * WW);
    #pragma unroll
    for (int dy = 0; dy < 4; dy++) {
        const int oy = ty0 + py + dy;
        unsigned lo = 0, hi = 0;
        #pragma unroll
        for (int p = 0; p < 4; p++) lo |= (acc[dy][p]     >= 1.f ? 1u : 0u) << (8 * p);
        #pragma unroll
        for (int p = 0; p < 4; p++) hi |= (acc[dy][p + 4] >= 1.f ? 1u : 0u) << (8 * p);
        uint2 v; v.x = lo; v.y = hi;
        *(uint2*)&gp[(size_t)oy * WW + ox] = v;
    }
}

// ---------------- Stage 3: combine 16 spike planes -> output ----------------
__global__ __launch_bounds__(256) void combine_kernel(
    const unsigned char* __restrict__ gsp, float* __restrict__ out)
{
    const int idx = blockIdx.x * 256 + threadIdx.x;   // 0 .. 4*65536-1 (uint granules)
    const int b = idx >> 16;
    const int r = idx & 65535;
    const unsigned* g = (const unsigned*)gsp;
    const int pb = b * 16;
    unsigned s = 0;
    #pragma unroll
    for (int o = 0; o < 4; o++) {
        unsigned g0 = g[(size_t)(pb + 4 * o + 0) * 65536 + r];
        unsigned g1 = g[(size_t)(pb + 4 * o + 1) * 65536 + r];
        unsigned g2 = g[(size_t)(pb + 4 * o + 2) * 65536 + r];
        unsigned g3 = g[(size_t)(pb + 4 * o + 3) * 65536 + r];
        s += ((g0 & ~g1) & 0x01010101u) + ((g2 & ~g3) & 0x01010101u);
    }
    float4 f;
    f.x = (float)(s & 255u);
    f.y = (float)((s >> 8) & 255u);
    f.z = (float)((s >> 16) & 255u);
    f.w = (float)(s >> 24);
    ((float4*)out)[idx] = f;
}

extern "C" void kernel_launch(void* const* d_in, const int* in_sizes, int n_in,
                              void* d_out, int out_size, void* d_ws, size_t ws_size,
                              hipStream_t stream)
{
    const float* inp = (const float*)d_in[0];   // (4,2,512,512) f32
    const float* Wb  = (const float*)d_in[1];   // (8,1,11,11)   f32
    const float* Wg  = (const float*)d_in[2];   // (16,1,23,23)  f32
    unsigned char* border = (unsigned char*)d_ws;                       // 16.78 MB
    unsigned char* gsp    = border + (size_t)NB * 16 * HH * WW;         // +16.78 MB
    float* out = (float*)d_out;                 // (4,512,512)   f32

    dim3 blk(256);
    dim3 g1(WW / T1, HH / T1, NB);          // 16x16x4 = 1024 blocks
    stage1_kernel<<<g1, blk, 0, stream>>>(inp, Wb, border);
    dim3 g2(WW / T2X, HH / T2Y, NB * 16);   // 8x4x64 = 2048 blocks
    stage2_kernel<<<g2, blk, 0, stream>>>(border, Wg, gsp);
    dim3 g3((NB * HH * WW / 4) / 256);      // 1024 blocks
    combine_kernel<<<g3, blk, 0, stream>>>(gsp, out);
}